// Round 5
// baseline (6305.232 us; speedup 1.0000x reference)
//
#include <hip/hip_runtime.h>

#define T_TOK 8192   // B*S tokens
#define DIM   768
#define NCB   8192   // codebook entries
#define KSEL  8
#define BT    64     // tokens per workgroup (1 per lane)
#define CTILE 32     // codes per block-tile (8 per wave)
#define BD    32     // d-chunk staged in LDS
#define XBUFQ 512    // float4 per x staging buffer
#define MST   33     // merge row stride in floats

typedef float v2f __attribute__((ext_vector_type(2)));

// 16B global->LDS DMA. Dest is wave-uniform base + lane*16 (HW rule); all
// per-lane scatter lives in the GLOBAL source address.
__device__ __forceinline__ void gload16(const float* g, float4* l) {
  __builtin_amdgcn_global_load_lds(
      (const __attribute__((address_space(1))) void*)g,
      (__attribute__((address_space(3))) void*)l, 16, 0, 0);
}

// ---------------------------------------------------------------------------
// Kernel A: ||row||^2 — bit-exact modern-numpy pairwise_sum (npyv/AVX-512
// W=16) over t[k]=fl32(v*v). [frozen: R5 green — do not change rounding]
// ---------------------------------------------------------------------------
__global__ __launch_bounds__(256) void sq_pairwise_kernel(
    const float* __restrict__ cb, const float* __restrict__ x,
    float* __restrict__ c2out, float* __restrict__ x2out)
{
  #pragma clang fp contract(off)
  __shared__ float part[32][8];
  const int tid = threadIdx.x;
  const int row = blockIdx.x * 32 + (tid >> 3);       // 0..16383
  const int b   = tid & 7;                            // 96-block index
  const float* src = (row < NCB) ? (cb + (size_t)row * DIM)
                                 : (x + (size_t)(row - NCB) * DIM);
  const float* a = src + 96 * b;

  float s[16];
  #pragma unroll
  for (int l = 0; l < 16; ++l) {
    float v, t;
    v = a[l];       t = v * v; float r0 = t;
    v = a[64 + l];  t = v * v; r0 = r0 + t;
    v = a[80 + l];  t = v * v; r0 = r0 + t;
    v = a[16 + l];  t = v * v; float r1 = t;
    v = a[32 + l];  t = v * v; float r2 = t;
    v = a[48 + l];  t = v * v; float r3 = t;
    s[l] = (r0 + r1) + (r2 + r3);
  }
  float t1[8], t2[4];
  #pragma unroll
  for (int i = 0; i < 8; ++i) t1[i] = s[i] + s[i + 8];
  #pragma unroll
  for (int j = 0; j < 4; ++j) t2[j] = t1[j] + t1[j + 4];
  part[tid >> 3][b] = (t2[0] + t2[2]) + (t2[1] + t2[3]);
  __syncthreads();

  if (b == 0) {
    const float* p = part[tid >> 3];
    float res = ((p[0] + p[1]) + (p[2] + p[3])) + ((p[4] + p[5]) + (p[6] + p[7]));
    if (row < NCB) c2out[row] = res;
    else           x2out[row - NCB] = res;
  }
}

// ---------------------------------------------------------------------------
// Kernel B: split-K distance + per-split exact top-8.
// Frozen arithmetic (R5): unfused SSE1 4-lane comb (lane = k&3, ascending k),
// reduce (l0+l2)+(l1+l3), neg = fl(fl(2*xc-x2)-c2), key = -neg (exact).
// R5 structure: wave = 64 tokens (1/lane) x 8 codes (R4 tiling), but the
// CODE operand now comes straight from GLOBAL memory with wave-uniform-valued
// addresses (one coalesced 16B L1 request + broadcast per load) — zero DS
// instructions on the c-path, vmcnt (not lgkm) so x-read pipelining is
// untouched. LDS holds only the double-buffered x chunk: 8 ds_read_b128 per
// chunk per thread vs 256 packed-VALU insts => VALU-bound.
// Loop order j-outer/q-inner: per-acc[j] accumulation order over q is
// ascending exactly as before => bit-exact. Register top-8 scan (ids ascend:
// n0 + w*8 + j; strict < keeps lowest id on ties); 4-wave merge via LDS.
// ---------------------------------------------------------------------------
__global__ __launch_bounds__(256, 4) void dist_topk_kernel(
    const float* __restrict__ x, const float* __restrict__ cb,
    const float* __restrict__ c2g, const float* __restrict__ x2g,
    float* __restrict__ ws, int ncodes)
{
  #pragma clang fp contract(off)
  __shared__ float4 smem4[1056];                 // 16896 B
  float* smem = (float*)smem4;
  // x buf b: smem4 + b*XBUFQ ([q][t], 512 f4, 1024B per quad-row)
  // post-loop overlay: md [64][MST] floats @0, mi [64][MST] ints @64*MST

  const int tid  = threadIdx.x;
  const int t0   = blockIdx.x * BT;
  const int nbeg = blockIdx.y * ncodes;
  const int lane = tid & 63;     // token within block
  const int w    = tid >> 6;     // wave id = code-group (8 codes)

  // x DMA: slot = w*64+lane -> (quad w, token lane); call 2 covers quad w+4.
  const float* xrow = x + (size_t)(t0 + lane) * DIM;
  float4* xdst = smem4 + (tid & ~63);            // + b*XBUFQ (+256 for call 2)

  const float x2r = x2g[t0 + lane];

  float bdist[KSEL]; int bid[KSEL];
  #pragma unroll
  for (int i = 0; i < KSEL; ++i) { bdist[i] = __builtin_inff(); bid[i] = 0x7fffffff; }
  float bmax = __builtin_inff(); int bmaxid = 0x7fffffff; int bslot = 0;

  for (int n0 = nbeg; n0 < nbeg + ncodes; n0 += CTILE) {
    v2f accL[8], accH[8];          // SSE lanes (0,1) and (2,3) for 8 codes
    #pragma unroll
    for (int j = 0; j < 8; ++j) { accL[j] = (v2f)0.f; accH[j] = (v2f)0.f; }

    // this wave's 8 codes (uniform-valued address per wave)
    const float* cbw = cb + (size_t)(n0 + w * 8) * DIM;

    {                              // stage chunk 0 -> buf0 (prev tile drained)
      gload16(xrow + w * 4,      xdst);
      gload16(xrow + 16 + w * 4, xdst + 256);
    }
    __syncthreads();               // chunk 0 visible (implicit vmcnt(0))

    for (int d0 = 0; d0 < DIM; d0 += BD) {
      const int buf = (d0 >> 5) & 1;
      const int dn = d0 + BD;
      if (dn < DIM) {              // issue next-chunk DMA into other buffer
        float4* xd = xdst + (buf ^ 1) * XBUFQ;
        gload16(xrow + dn + w * 4,      xd);
        gload16(xrow + dn + 16 + w * 4, xd + 256);
      }

      // my token's 8 quads of this chunk (2-way bank aliasing = free)
      const char* xb = (const char*)(smem4 + buf * XBUFQ) + lane * 16;
      float4 xv[8];
      #pragma unroll
      for (int q = 0; q < 8; ++q) xv[q] = *(const float4*)(xb + q * 1024);

      const float* cch = cbw + d0;
      #pragma unroll
      for (int j = 0; j < 8; ++j) {
        const float* cj = cch + (size_t)j * DIM;
        #pragma unroll
        for (int q = 0; q < 8; ++q) {      // ascending q = ascending k (frozen)
          const float4 cv = *(const float4*)(cj + q * 4);
          v2f xlo, xhi, clo, chi, p;
          xlo[0] = xv[q].x; xlo[1] = xv[q].y;
          xhi[0] = xv[q].z; xhi[1] = xv[q].w;
          clo[0] = cv.x;    clo[1] = cv.y;
          chi[0] = cv.z;    chi[1] = cv.w;
          p = xlo * clo; accL[j] = accL[j] + p;   // independent fl32 mul/add
          p = xhi * chi; accH[j] = accH[j] + p;
        }
      }
      __syncthreads();             // my reads done + next-chunk DMA landed
    }

    // ---- combine (frozen order) + register-resident top-8 scan ----
    #pragma unroll
    for (int j = 0; j < 8; ++j) {
      const float c2 = c2g[n0 + w * 8 + j];
      // einsum reduce (l0+l2)+(l1+l3), then literal numpy combine
      const float xc = (accL[j][0] + accH[j][0]) + (accL[j][1] + accH[j][1]);
      const float s  = 2.0f * xc - x2r;
      const float dval = -(s - c2);
      const int   id   = n0 + w * 8 + j;
      if (dval < bmax) {
        #pragma unroll
        for (int q = 0; q < KSEL; ++q)
          if (q == bslot) { bdist[q] = dval; bid[q] = id; }
        bmax = bdist[0]; bmaxid = bid[0]; bslot = 0;
        #pragma unroll
        for (int q = 1; q < KSEL; ++q)
          if (bdist[q] > bmax || (bdist[q] == bmax && bid[q] > bmaxid)) {
            bmax = bdist[q]; bmaxid = bid[q]; bslot = q;
          }
      }
    }
    // next tile's staging is safe: last chunk's barrier drained all reads
  }

  // ---- merge 4 waves x 8 -> this split's top-8 per token; write to ws ----
  float* md = smem;                    // [64][MST]
  int*   mi = (int*)smem + 64 * MST;   // [64][MST]
  #pragma unroll
  for (int j = 0; j < KSEL; ++j) {
    md[lane * MST + w * KSEL + j] = bdist[j];
    mi[lane * MST + w * KSEL + j] = bid[j];
  }
  __syncthreads();
  if (tid < BT) {
    float* mdt = md + tid * MST;
    int*   mit = mi + tid * MST;
    const size_t base = ((size_t)blockIdx.y * T_TOK + (t0 + tid)) * 16;
    for (int r = 0; r < KSEL; ++r) {
      float best = __builtin_inff(); int bestid = 0x7fffffff; int bs = 0;
      for (int s = 0; s < 32; ++s) {
        const float dv = mdt[s]; const int iv = mit[s];
        if (dv < best || (dv == best && iv < bestid)) { best = dv; bestid = iv; bs = s; }
      }
      mdt[bs] = __builtin_inff();
      ws[base + r] = best;
      ((int*)ws)[base + 8 + r] = bestid;
    }
  }
}

// ---------------------------------------------------------------------------
// Kernel C: exact (val,id)-lex merge of nsplit*8 candidates -> final ids,
// fused with the gather-mean of the 8 selected rows.
// ---------------------------------------------------------------------------
__global__ __launch_bounds__(192) void merge_gather_kernel(
    const float* __restrict__ cb, const float* __restrict__ ws,
    float* __restrict__ out, float* __restrict__ out_ids, int nsplit)
{
  __shared__ float mv[64];
  __shared__ int   mid[64];
  __shared__ int   ssel[KSEL];

  const int t   = blockIdx.x;
  const int tid = threadIdx.x;
  const int ncand = nsplit * KSEL;

  if (tid < ncand) {
    const int s = tid >> 3, r = tid & 7;
    const size_t base = ((size_t)s * T_TOK + t) * 16;
    mv[tid]  = ws[base + r];
    mid[tid] = ((const int*)ws)[base + 8 + r];
  }
  __syncthreads();

  if (tid == 0) {
    for (int r = 0; r < KSEL; ++r) {
      float best = __builtin_inff(); int bestid = 0x7fffffff; int bs = 0;
      for (int s = 0; s < ncand; ++s) {
        const float dv = mv[s]; const int iv = mid[s];
        if (dv < best || (dv == best && iv < bestid)) { best = dv; bestid = iv; bs = s; }
      }
      mv[bs] = __builtin_inff();
      ssel[r] = bestid;
      out_ids[(size_t)t * KSEL + r] = (float)bestid;
    }
  }
  __syncthreads();

  float4 s4 = make_float4(0.f, 0.f, 0.f, 0.f);
  #pragma unroll
  for (int r = 0; r < KSEL; ++r) {
    const float4 v = *(const float4*)(cb + (size_t)ssel[r] * DIM + tid * 4);
    s4.x += v.x; s4.y += v.y; s4.z += v.z; s4.w += v.w;
  }
  s4.x *= 0.125f; s4.y *= 0.125f; s4.z *= 0.125f; s4.w *= 0.125f;
  *(float4*)(out + (size_t)t * DIM + tid * 4) = s4;
}

extern "C" void kernel_launch(void* const* d_in, const int* in_sizes, int n_in,
                              void* d_out, int out_size, void* d_ws, size_t ws_size,
                              hipStream_t stream) {
  (void)in_sizes; (void)n_in; (void)out_size;
  const float* x   = (const float*)d_in[0];
  const float* cbk = (const float*)d_in[1];
  float* out     = (float*)d_out;
  float* c2buf   = out;                   // out[0:8192], overwritten later
  float* x2buf   = out + NCB;             // out[8192:16384], overwritten later
  float* out_ids = out + (size_t)T_TOK * DIM;
  float* ws      = (float*)d_ws;

  int nsplit = 1;
  for (int s = 8; s >= 1; s >>= 1) {
    if ((size_t)s * T_TOK * 16 * 4 <= ws_size) { nsplit = s; break; }
  }
  const int ncodes = NCB / nsplit;        // multiple of CTILE for all nsplit

  sq_pairwise_kernel<<<(NCB + T_TOK) / 32, 256, 0, stream>>>(cbk, x, c2buf, x2buf);
  dist_topk_kernel<<<dim3(T_TOK / BT, nsplit), 256, 0, stream>>>(
      x, cbk, c2buf, x2buf, ws, ncodes);
  merge_gather_kernel<<<T_TOK, 192, 0, stream>>>(cbk, ws, out, out_ids, nsplit);
}

// Round 6
// 2599.707 us; speedup vs baseline: 2.4254x; 2.4254x over previous
//
#include <hip/hip_runtime.h>

#define T_TOK 8192   // B*S tokens
#define DIM   768
#define NCB   8192   // codebook entries
#define KSEL  8
#define BT    64     // tokens per workgroup (1 per lane)
#define CTILE 32     // codes per block-tile (8 per wave)
#define BD    32     // d-chunk staged in LDS
#define XBUFQ 512    // float4 per x staging buffer
#define MST   33     // merge row stride in floats

typedef float v2f  __attribute__((ext_vector_type(2)));
typedef float v16f __attribute__((ext_vector_type(16)));

// 16B global->LDS DMA. Dest is wave-uniform base + lane*16 (HW rule); all
// per-lane scatter lives in the GLOBAL source address.
__device__ __forceinline__ void gload16(const float* g, float4* l) {
  __builtin_amdgcn_global_load_lds(
      (const __attribute__((address_space(1))) void*)g,
      (__attribute__((address_space(3))) void*)l, 16, 0, 0);
}

// extract SGPR pair k (floats 2k,2k+1) from a 16-wide SGPR vector
#define P2(C, k) (__builtin_shufflevector((C), (C), 2*(k), 2*(k)+1))

// two s_load_dwordx16: 32 floats (one code's 32-d chunk) into SGPRs
#define SLOAD(d0_, d1_, ap)                                                  \
  asm volatile("s_load_dwordx16 %0, %2, 0x0\n\t"                             \
               "s_load_dwordx16 %1, %2, 0x40"                                \
               : "=s"(d0_), "=s"(d1_) : "s"(ap));

#define WAITLG asm volatile("s_waitcnt lgkmcnt(0)" ::: "memory");

// 4 quads of unfused MAC: t=fl(c*x) then acc=fl(acc+t), SGPR c as src0.
// mul->add distance 2 insts covers VALU forwarding latency.
#define MACH(aL, aH, C, x0l, x0h, x1l, x1h, x2l, x2h, x3l, x3h)              \
  { v2f t0_, t1_;                                                            \
    asm volatile(                                                            \
      "v_pk_mul_f32 %[t0], %[c0], %[y0l]\n\t"                                \
      "v_pk_mul_f32 %[t1], %[c1], %[y0h]\n\t"                                \
      "v_pk_add_f32 %[al], %[al], %[t0]\n\t"                                 \
      "v_pk_add_f32 %[ah], %[ah], %[t1]\n\t"                                 \
      "v_pk_mul_f32 %[t0], %[c2], %[y1l]\n\t"                                \
      "v_pk_mul_f32 %[t1], %[c3], %[y1h]\n\t"                                \
      "v_pk_add_f32 %[al], %[al], %[t0]\n\t"                                 \
      "v_pk_add_f32 %[ah], %[ah], %[t1]\n\t"                                 \
      "v_pk_mul_f32 %[t0], %[c4], %[y2l]\n\t"                                \
      "v_pk_mul_f32 %[t1], %[c5], %[y2h]\n\t"                                \
      "v_pk_add_f32 %[al], %[al], %[t0]\n\t"                                 \
      "v_pk_add_f32 %[ah], %[ah], %[t1]\n\t"                                 \
      "v_pk_mul_f32 %[t0], %[c6], %[y3l]\n\t"                                \
      "v_pk_mul_f32 %[t1], %[c7], %[y3h]\n\t"                                \
      "v_pk_add_f32 %[al], %[al], %[t0]\n\t"                                 \
      "v_pk_add_f32 %[ah], %[ah], %[t1]"                                     \
      : [al]"+v"(aL), [ah]"+v"(aH), [t0]"=&v"(t0_), [t1]"=&v"(t1_)           \
      : [c0]"s"(P2(C,0)), [c1]"s"(P2(C,1)), [c2]"s"(P2(C,2)),                \
        [c3]"s"(P2(C,3)), [c4]"s"(P2(C,4)), [c5]"s"(P2(C,5)),                \
        [c6]"s"(P2(C,6)), [c7]"s"(P2(C,7)),                                  \
        [y0l]"v"(x0l), [y0h]"v"(x0h), [y1l]"v"(x1l), [y1h]"v"(x1h),          \
        [y2l]"v"(x2l), [y2h]"v"(x2h), [y3l]"v"(x3l), [y3h]"v"(x3h));         \
  }

// one code j: quads 0-3 from C0, quads 4-7 from C1 (ascending q per chain)
#define MACJ(j_, C0_, C1_)                                                   \
  MACH(accL[j_], accH[j_], C0_,                                              \
       xl[0], xh[0], xl[1], xh[1], xl[2], xh[2], xl[3], xh[3])               \
  MACH(accL[j_], accH[j_], C1_,                                              \
       xl[4], xh[4], xl[5], xh[5], xl[6], xh[6], xl[7], xh[7])

// ---------------------------------------------------------------------------
// Kernel A: ||row||^2 — bit-exact modern-numpy pairwise_sum (npyv/AVX-512
// W=16) over t[k]=fl32(v*v). [frozen: R5 green — do not change rounding]
// ---------------------------------------------------------------------------
__global__ __launch_bounds__(256) void sq_pairwise_kernel(
    const float* __restrict__ cb, const float* __restrict__ x,
    float* __restrict__ c2out, float* __restrict__ x2out)
{
  #pragma clang fp contract(off)
  __shared__ float part[32][8];
  const int tid = threadIdx.x;
  const int row = blockIdx.x * 32 + (tid >> 3);       // 0..16383
  const int b   = tid & 7;                            // 96-block index
  const float* src = (row < NCB) ? (cb + (size_t)row * DIM)
                                 : (x + (size_t)(row - NCB) * DIM);
  const float* a = src + 96 * b;

  float s[16];
  #pragma unroll
  for (int l = 0; l < 16; ++l) {
    float v, t;
    v = a[l];       t = v * v; float r0 = t;
    v = a[64 + l];  t = v * v; r0 = r0 + t;
    v = a[80 + l];  t = v * v; r0 = r0 + t;
    v = a[16 + l];  t = v * v; float r1 = t;
    v = a[32 + l];  t = v * v; float r2 = t;
    v = a[48 + l];  t = v * v; float r3 = t;
    s[l] = (r0 + r1) + (r2 + r3);
  }
  float t1[8], t2[4];
  #pragma unroll
  for (int i = 0; i < 8; ++i) t1[i] = s[i] + s[i + 8];
  #pragma unroll
  for (int j = 0; j < 4; ++j) t2[j] = t1[j] + t1[j + 4];
  part[tid >> 3][b] = (t2[0] + t2[2]) + (t2[1] + t2[3]);
  __syncthreads();

  if (b == 0) {
    const float* p = part[tid >> 3];
    float res = ((p[0] + p[1]) + (p[2] + p[3])) + ((p[4] + p[5]) + (p[6] + p[7]));
    if (row < NCB) c2out[row] = res;
    else           x2out[row - NCB] = res;
  }
}

// ---------------------------------------------------------------------------
// Kernel B: split-K distance + per-split exact top-8.
// Frozen arithmetic (R5): unfused SSE1 4-lane comb (lane = k&3, ascending k),
// reduce (l0+l2)+(l1+l3), neg = fl(fl(2*xc-x2)-c2), key = -neg (exact).
// R6 structure: wave = 64 tokens (1/lane) x 8 codes (R4/R5 tiling, twice
// proven bit-exact). CODE operand now rides the SCALAR pipe: per chunk per
// code, 2x s_load_dwordx16 into SGPRs (A/B double-buffered, lgkmcnt(0)
// between — safe for SMEM out-of-order completion), consumed directly as
// the SGPR src0 of inline-asm v_pk_mul_f32/v_pk_add_f32 (unfused, ascending
// q per chain — op-for-op identical values to R5 => bit-exact). LDS carries
// only the double-buffered x chunk: 8 ds_read_b128/chunk/thread vs 256
// packed-VALU insts => VALU-bound. Register top-8; 4-wave LDS merge.
// ---------------------------------------------------------------------------
__global__ __launch_bounds__(256, 4) void dist_topk_kernel(
    const float* __restrict__ x, const float* __restrict__ cb,
    const float* __restrict__ c2g, const float* __restrict__ x2g,
    float* __restrict__ ws, int ncodes)
{
  #pragma clang fp contract(off)
  __shared__ float4 smem4[1056];                 // 16896 B
  float* smem = (float*)smem4;
  // x buf b: smem4 + b*XBUFQ ([q][t], 512 f4, 1024B per quad-row)
  // post-loop overlay: md [64][MST] floats @0, mi [64][MST] ints @64*MST

  const int tid  = threadIdx.x;
  const int t0   = blockIdx.x * BT;
  const int nbeg = blockIdx.y * ncodes;
  const int lane = tid & 63;     // token within block
  const int w    = tid >> 6;     // wave id = code-group (8 codes)
  const int wS   = __builtin_amdgcn_readfirstlane(w);   // uniform copy

  // x DMA: slot = w*64+lane -> (quad w, token lane); call 2 covers quad w+4.
  const float* xrow = x + (size_t)(t0 + lane) * DIM;
  float4* xdst = smem4 + (tid & ~63);            // + b*XBUFQ (+256 for call 2)

  const float x2r = x2g[t0 + lane];

  float bdist[KSEL]; int bid[KSEL];
  #pragma unroll
  for (int i = 0; i < KSEL; ++i) { bdist[i] = __builtin_inff(); bid[i] = 0x7fffffff; }
  float bmax = __builtin_inff(); int bmaxid = 0x7fffffff; int bslot = 0;

  for (int n0 = nbeg; n0 < nbeg + ncodes; n0 += CTILE) {
    v2f accL[8], accH[8];          // SSE lanes (0,1) and (2,3) for 8 codes
    #pragma unroll
    for (int j = 0; j < 8; ++j) { accL[j] = (v2f)0.f; accH[j] = (v2f)0.f; }

    // byte base of this wave's 8 codes (scalar/uniform)
    const uint64_t cbT = (uint64_t)(uintptr_t)cb
                       + (uint64_t)(n0 + wS * 8) * (DIM * 4);

    {                              // stage chunk 0 -> buf0 (prev tile drained)
      gload16(xrow + w * 4,      xdst);
      gload16(xrow + 16 + w * 4, xdst + 256);
    }
    __syncthreads();               // chunk 0 visible (implicit vmcnt(0))

    for (int d0 = 0; d0 < DIM; d0 += BD) {
      const int buf = (d0 >> 5) & 1;
      const int dn = d0 + BD;
      if (dn < DIM) {              // issue next-chunk DMA into other buffer
        float4* xd = xdst + (buf ^ 1) * XBUFQ;
        gload16(xrow + dn + w * 4,      xd);
        gload16(xrow + dn + 16 + w * 4, xd + 256);
      }

      // my token's 8 quads of this chunk (2-way bank aliasing = free)
      const char* xb = (const char*)(smem4 + buf * XBUFQ) + lane * 16;
      v2f xl[8], xh[8];
      #pragma unroll
      for (int q = 0; q < 8; ++q) {
        const float4 xv = *(const float4*)(xb + q * 1024);
        xl[q] = (v2f){xv.x, xv.y};
        xh[q] = (v2f){xv.z, xv.w};
      }

      const uint64_t ca = cbT + (uint64_t)d0 * 4;
      v16f A0, A1, B0, B1;
      SLOAD(A0, A1, ca)
      WAITLG                                        // A(j0) + xv drained
      SLOAD(B0, B1, ca + 1 * 3072)  MACJ(0, A0, A1) WAITLG
      SLOAD(A0, A1, ca + 2 * 3072)  MACJ(1, B0, B1) WAITLG
      SLOAD(B0, B1, ca + 3 * 3072)  MACJ(2, A0, A1) WAITLG
      SLOAD(A0, A1, ca + 4 * 3072)  MACJ(3, B0, B1) WAITLG
      SLOAD(B0, B1, ca + 5 * 3072)  MACJ(4, A0, A1) WAITLG
      SLOAD(A0, A1, ca + 6 * 3072)  MACJ(5, B0, B1) WAITLG
      SLOAD(B0, B1, ca + 7 * 3072)  MACJ(6, A0, A1) WAITLG
      MACJ(7, B0, B1)

      __syncthreads();             // my reads done + next-chunk DMA landed
    }

    // ---- combine (frozen order) + register-resident top-8 scan ----
    #pragma unroll
    for (int j = 0; j < 8; ++j) {
      const float c2 = c2g[n0 + w * 8 + j];
      // einsum reduce (l0+l2)+(l1+l3), then literal numpy combine
      const float xc = (accL[j][0] + accH[j][0]) + (accL[j][1] + accH[j][1]);
      const float s  = 2.0f * xc - x2r;
      const float dval = -(s - c2);
      const int   id   = n0 + w * 8 + j;
      if (dval < bmax) {
        #pragma unroll
        for (int q = 0; q < KSEL; ++q)
          if (q == bslot) { bdist[q] = dval; bid[q] = id; }
        bmax = bdist[0]; bmaxid = bid[0]; bslot = 0;
        #pragma unroll
        for (int q = 1; q < KSEL; ++q)
          if (bdist[q] > bmax || (bdist[q] == bmax && bid[q] > bmaxid)) {
            bmax = bdist[q]; bmaxid = bid[q]; bslot = q;
          }
      }
    }
    // next tile's staging is safe: last chunk's barrier drained all reads
  }

  // ---- merge 4 waves x 8 -> this split's top-8 per token; write to ws ----
  float* md = smem;                    // [64][MST]
  int*   mi = (int*)smem + 64 * MST;   // [64][MST]
  #pragma unroll
  for (int j = 0; j < KSEL; ++j) {
    md[lane * MST + w * KSEL + j] = bdist[j];
    mi[lane * MST + w * KSEL + j] = bid[j];
  }
  __syncthreads();
  if (tid < BT) {
    float* mdt = md + tid * MST;
    int*   mit = mi + tid * MST;
    const size_t base = ((size_t)blockIdx.y * T_TOK + (t0 + tid)) * 16;
    for (int r = 0; r < KSEL; ++r) {
      float best = __builtin_inff(); int bestid = 0x7fffffff; int bs = 0;
      for (int s = 0; s < 32; ++s) {
        const float dv = mdt[s]; const int iv = mit[s];
        if (dv < best || (dv == best && iv < bestid)) { best = dv; bestid = iv; bs = s; }
      }
      mdt[bs] = __builtin_inff();
      ws[base + r] = best;
      ((int*)ws)[base + 8 + r] = bestid;
    }
  }
}

// ---------------------------------------------------------------------------
// Kernel C: exact (val,id)-lex merge of nsplit*8 candidates -> final ids,
// fused with the gather-mean of the 8 selected rows.
// ---------------------------------------------------------------------------
__global__ __launch_bounds__(192) void merge_gather_kernel(
    const float* __restrict__ cb, const float* __restrict__ ws,
    float* __restrict__ out, float* __restrict__ out_ids, int nsplit)
{
  __shared__ float mv[64];
  __shared__ int   mid[64];
  __shared__ int   ssel[KSEL];

  const int t   = blockIdx.x;
  const int tid = threadIdx.x;
  const int ncand = nsplit * KSEL;

  if (tid < ncand) {
    const int s = tid >> 3, r = tid & 7;
    const size_t base = ((size_t)s * T_TOK + t) * 16;
    mv[tid]  = ws[base + r];
    mid[tid] = ((const int*)ws)[base + 8 + r];
  }
  __syncthreads();

  if (tid == 0) {
    for (int r = 0; r < KSEL; ++r) {
      float best = __builtin_inff(); int bestid = 0x7fffffff; int bs = 0;
      for (int s = 0; s < ncand; ++s) {
        const float dv = mv[s]; const int iv = mid[s];
        if (dv < best || (dv == best && iv < bestid)) { best = dv; bestid = iv; bs = s; }
      }
      mv[bs] = __builtin_inff();
      ssel[r] = bestid;
      out_ids[(size_t)t * KSEL + r] = (float)bestid;
    }
  }
  __syncthreads();

  float4 s4 = make_float4(0.f, 0.f, 0.f, 0.f);
  #pragma unroll
  for (int r = 0; r < KSEL; ++r) {
    const float4 v = *(const float4*)(cb + (size_t)ssel[r] * DIM + tid * 4);
    s4.x += v.x; s4.y += v.y; s4.z += v.z; s4.w += v.w;
  }
  s4.x *= 0.125f; s4.y *= 0.125f; s4.z *= 0.125f; s4.w *= 0.125f;
  *(float4*)(out + (size_t)t * DIM + tid * 4) = s4;
}

extern "C" void kernel_launch(void* const* d_in, const int* in_sizes, int n_in,
                              void* d_out, int out_size, void* d_ws, size_t ws_size,
                              hipStream_t stream) {
  (void)in_sizes; (void)n_in; (void)out_size;
  const float* x   = (const float*)d_in[0];
  const float* cbk = (const float*)d_in[1];
  float* out     = (float*)d_out;
  float* c2buf   = out;                   // out[0:8192], overwritten later
  float* x2buf   = out + NCB;             // out[8192:16384], overwritten later
  float* out_ids = out + (size_t)T_TOK * DIM;
  float* ws      = (float*)d_ws;

  int nsplit = 1;
  for (int s = 8; s >= 1; s >>= 1) {
    if ((size_t)s * T_TOK * 16 * 4 <= ws_size) { nsplit = s; break; }
  }
  const int ncodes = NCB / nsplit;        // multiple of CTILE for all nsplit

  sq_pairwise_kernel<<<(NCB + T_TOK) / 32, 256, 0, stream>>>(cbk, x, c2buf, x2buf);
  dist_topk_kernel<<<dim3(T_TOK / BT, nsplit), 256, 0, stream>>>(
      x, cbk, c2buf, x2buf, ws, ncodes);
  merge_gather_kernel<<<T_TOK, 192, 0, stream>>>(cbk, ws, out, out_ids, nsplit);
}